// Round 7
// baseline (578.360 us; speedup 1.0000x reference)
//
#include <hip/hip_runtime.h>
#include <hip/hip_cooperative_groups.h>
#include <math.h>

namespace cg = cooperative_groups;

#define LEAKY(v) ((v) > 0.0f ? (v) : 0.01f * (v))

typedef _Float16 v8h __attribute__((ext_vector_type(8)));
typedef float v4f __attribute__((ext_vector_type(4)));

// ================= cooperative prologue: splitW + cnt zero + count + scan + dinv + fill
// (5 launches -> 1; phases separated by grid.sync()) =================
__global__ __launch_bounds__(256) void k_prol(
    const float* __restrict__ W1, const float* __restrict__ W2, const float* __restrict__ W3,
    _Float16* __restrict__ th0, _Float16* __restrict__ tl0,
    _Float16* __restrict__ th1, _Float16* __restrict__ tl1,
    _Float16* __restrict__ th2, _Float16* __restrict__ tl2,
    const int* __restrict__ ei, int* __restrict__ cnt, int* __restrict__ rowptr,
    int* __restrict__ bsum, float* __restrict__ dinv, int2* __restrict__ adj,
    int N, int E) {
    cg::grid_group grid = cg::this_grid();
    __shared__ int s[256];
    const int t = threadIdx.x;
    const int gtid = blockIdx.x * 256 + t;
    const int gsz = gridDim.x * 256;

    // P0: zero cnt + W split (independent work, one pass)
    for (int i = gtid; i < N; i += gsz) cnt[i] = 0;
    for (int idx = gtid; idx < 224 * 208 * 3; idx += gsz) {
        int layer = idx / (224 * 208);
        int r = idx - layer * (224 * 208);
        int k = r / 208, c = r - k * 208;
        const float* W = (layer == 0) ? W1 : (layer == 1) ? W2 : W3;
        _Float16* Th = (layer == 0) ? th0 : (layer == 1) ? th1 : th2;
        _Float16* Tl = (layer == 0) ? tl0 : (layer == 1) ? tl1 : tl2;
        float v = (k < 200 && c < 200) ? W[k * 200 + c] : 0.0f;
        _Float16 hi = (_Float16)v;
        Th[c * 224 + k] = hi;
        Tl[c * 224 + k] = (_Float16)(v - (float)hi);
    }
    grid.sync();

    // P1: degree count (by destination)
    for (int e = gtid; e < E; e += gsz) atomicAdd(&cnt[ei[E + e]], 1);
    grid.sync();

    // P2a: per-256-chunk exclusive scan; chunk totals -> bsum
    const int nchunk = (N + 255) / 256;   // 196 <= 256
    for (int c = blockIdx.x; c < nchunk; c += gridDim.x) {
        int i = c * 256 + t;
        int v = (i < N) ? cnt[i] : 0;
        s[t] = v;
        __syncthreads();
        for (int off = 1; off < 256; off <<= 1) {
            int u = (t >= off) ? s[t - off] : 0;
            __syncthreads();
            s[t] += u;
            __syncthreads();
        }
        if (i < N) rowptr[i] = s[t] - v;
        if (t == 255) bsum[c] = s[255];
        __syncthreads();
    }
    grid.sync();

    // P2b: each block redundantly scans bsum (nchunk<=256), adds base, computes dinv
    for (int c = blockIdx.x; c < nchunk; c += gridDim.x) {
        int v = (t < nchunk) ? bsum[t] : 0;
        s[t] = v;
        __syncthreads();
        for (int off = 1; off < 256; off <<= 1) {
            int u = (t >= off) ? s[t - off] : 0;
            __syncthreads();
            s[t] += u;
            __syncthreads();
        }
        int base = c ? s[c - 1] : 0;
        int i = c * 256 + t;
        if (i < N) {
            rowptr[i] += base;
            dinv[i] = rsqrtf(1.0f + (float)cnt[i]);  // +1 self-loop
        }
        __syncthreads();
    }
    grid.sync();

    // P3: fill (atomic cursor on rowptr; after this rowptr[d]=end(d), start = rowptr[d-1])
    for (int e = gtid; e < E; e += gsz) {
        int sv = ei[e], d = ei[E + e];
        int pos = atomicAdd(&rowptr[d], 1);
        adj[pos] = make_int2(sv, __float_as_int(dinv[sv] * dinv[d]));
    }
}

// ================= layer-1 GEMM with FUSED 4-wide gather, 128-row tile,
// reg-staged double-buffered W pipeline (1 barrier per K-step):
// T = leaky((Ahat x)@W0 + b0) @ W1.
__global__ __launch_bounds__(512, 4) void k_gemm200_mfma_l0(const float* __restrict__ x,
                                                            const float* __restrict__ dinv,
                                                            const int* __restrict__ rowptr,
                                                            const int2* __restrict__ adj,
                                                            const float* __restrict__ W0,
                                                            const float* __restrict__ b0,
                                                            const _Float16* __restrict__ Wth,
                                                            const _Float16* __restrict__ Wtl,
                                                            _Float16* __restrict__ T, int M) {
    __shared__ _Float16 Wsh[2][208 * 32];
    __shared__ _Float16 Wsl[2][208 * 32];
    __shared__ float W0s[4][200];
    __shared__ float b0s[200];
    const int tid  = threadIdx.x;
    const int lane = tid & 63;
    const int wid  = tid >> 6;       // 0..7
    const int quad = lane >> 4;
    const int l16  = lane & 15;
    const int rowA = blockIdx.x * 128 + wid * 16 + l16;
    const int rowAc = min(rowA, M - 1);

    // W stage-reg geometry: 832 uint4 per half-tile over 512 threads
    const int nr0 = tid >> 2, p0 = tid & 3;
    const bool two = (tid < 320);
    const int nr1 = nr0 + 128;
    uint4 rh0, rl0, rh1, rl1;
    // issue k0=0 W loads FIRST (latency hides under gather + W0 staging)
    rh0 = *(const uint4*)&Wth[nr0 * 224 + p0 * 8];
    rl0 = *(const uint4*)&Wtl[nr0 * 224 + p0 * 8];
    if (two) {
        rh1 = *(const uint4*)&Wth[nr1 * 224 + p0 * 8];
        rl1 = *(const uint4*)&Wtl[nr1 * 224 + p0 * 8];
    }

    // stage W0/b0 (read after first barrier)
    for (int idx = tid; idx < 1000; idx += 512) {
        if (idx < 800) W0s[idx / 200][idx % 200] = W0[idx];
        else b0s[idx - 800] = b0[idx - 800];
    }

    // ---- fused gather4 ----
    float w0n = dinv[rowAc]; w0n *= w0n;
    float4 xv = ((const float4*)x)[rowAc];
    float4 pxv = make_float4(xv.x * w0n, xv.y * w0n, xv.z * w0n, xv.w * w0n);
    {
        int lo = rowAc ? rowptr[rowAc - 1] : 0;
        int hi = rowptr[rowAc];
        for (int j = lo; j < hi; ++j) {
            int2 cw = adj[j];
            float w = __int_as_float(cw.y);
            float4 sv = ((const float4*)x)[cw.x];
            pxv.x += sv.x * w; pxv.y += sv.y * w; pxv.z += sv.z * w; pxv.w += sv.w * w;
        }
    }

    v4f acc[13];
#pragma unroll
    for (int t = 0; t < 13; ++t) acc[t] = 0.0f;

#pragma unroll
    for (int kc = 0; kc < 7; ++kc) {
        const int k0 = kc * 32;
        const int buf = kc & 1;
        // write staged regs -> LDS[buf] (prev iter's MFMA read buf^1: no WAR)
        *(uint4*)&Wsh[buf][nr0 * 32 + p0 * 8] = rh0;
        *(uint4*)&Wsl[buf][nr0 * 32 + p0 * 8] = rl0;
        if (two) {
            *(uint4*)&Wsh[buf][nr1 * 32 + p0 * 8] = rh1;
            *(uint4*)&Wsl[buf][nr1 * 32 + p0 * 8] = rl1;
        }
        // issue next K-step's W loads (latency hides under MFMA below)
        if (kc < 6) {
            rh0 = *(const uint4*)&Wth[nr0 * 224 + (k0 + 32) + p0 * 8];
            rl0 = *(const uint4*)&Wtl[nr0 * 224 + (k0 + 32) + p0 * 8];
            if (two) {
                rh1 = *(const uint4*)&Wth[nr1 * 224 + (k0 + 32) + p0 * 8];
                rl1 = *(const uint4*)&Wtl[nr1 * 224 + (k0 + 32) + p0 * 8];
            }
        }
        __syncthreads();
        // A fragment (VALU, from registers + staged W0s)
        v8h ah, al;
        int kb = k0 + quad * 8;
        if (kb < 200) {
#pragma unroll
            for (int j = 0; j < 8; ++j) {
                int k = kb + j;
                float pv = pxv.x * W0s[0][k] + pxv.y * W0s[1][k]
                         + pxv.z * W0s[2][k] + pxv.w * W0s[3][k] + b0s[k];
                pv = LEAKY(pv);
                _Float16 h = (_Float16)pv;
                ah[j] = h;
                al[j] = (_Float16)(pv - (float)h);
            }
        } else {
#pragma unroll
            for (int j = 0; j < 8; ++j) { ah[j] = (_Float16)0.0f; al[j] = (_Float16)0.0f; }
        }
#pragma unroll
        for (int t = 0; t < 13; ++t) {
            int nidx = (t * 16 + l16) * 32 + quad * 8;
            v8h wh = *(const v8h*)&Wsh[buf][nidx];
            v8h wl = *(const v8h*)&Wsl[buf][nidx];
            acc[t] = __builtin_amdgcn_mfma_f32_16x16x32_f16(ah, wh, acc[t], 0, 0, 0);
            acc[t] = __builtin_amdgcn_mfma_f32_16x16x32_f16(ah, wl, acc[t], 0, 0, 0);
            acc[t] = __builtin_amdgcn_mfma_f32_16x16x32_f16(al, wh, acc[t], 0, 0, 0);
        }
    }
    const int rb = blockIdx.x * 128 + wid * 16 + quad * 4;
#pragma unroll
    for (int t = 0; t < 13; ++t) {
        int c = t * 16 + l16;
        if (c < 200) {
#pragma unroll
            for (int e = 0; e < 4; ++e) {
                int r = rb + e;
                if (r < M) T[(size_t)r * 200 + c] = (_Float16)acc[t][e];
            }
        }
    }
}

// ================= layers 2-3 GEMM, 128-row tile, A-prefetch + pipelined W:
// T = leaky(P + bprev) @ W =================
__global__ __launch_bounds__(512, 4) void k_gemm200_mfma(const _Float16* __restrict__ P,
                                                         const float* __restrict__ bias,
                                                         const _Float16* __restrict__ Wth,
                                                         const _Float16* __restrict__ Wtl,
                                                         _Float16* __restrict__ T, int M) {
    __shared__ _Float16 Wsh[2][208 * 32];
    __shared__ _Float16 Wsl[2][208 * 32];
    __shared__ float bS[200];
    const int tid  = threadIdx.x;
    const int lane = tid & 63;
    const int wid  = tid >> 6;       // 0..7
    const int quad = lane >> 4;
    const int l16  = lane & 15;
    const int rowA = blockIdx.x * 128 + wid * 16 + l16;
    const int rowAc = min(rowA, M - 1);
    const _Float16* Prow = P + (size_t)rowAc * 200;

    const int nr0 = tid >> 2, p0 = tid & 3;
    const bool two = (tid < 320);
    const int nr1 = nr0 + 128;
    uint4 rh0, rl0, rh1, rl1;
    rh0 = *(const uint4*)&Wth[nr0 * 224 + p0 * 8];
    rl0 = *(const uint4*)&Wtl[nr0 * 224 + p0 * 8];
    if (two) {
        rh1 = *(const uint4*)&Wth[nr1 * 224 + p0 * 8];
        rl1 = *(const uint4*)&Wtl[nr1 * 224 + p0 * 8];
    }
    if (tid < 200) bS[tid] = bias[tid];

    // prefetch ALL A chunks (7 independent loads, one latency)
    v8h pch[7];
#pragma unroll
    for (int kc = 0; kc < 7; ++kc) {
        int kb = kc * 32 + quad * 8;
        if (kb < 200) {
            pch[kc] = *(const v8h*)(Prow + kb);
        } else {
#pragma unroll
            for (int j = 0; j < 8; ++j) pch[kc][j] = (_Float16)0.0f;
        }
    }

    v4f acc[13];
#pragma unroll
    for (int t = 0; t < 13; ++t) acc[t] = 0.0f;

#pragma unroll
    for (int kc = 0; kc < 7; ++kc) {
        const int k0 = kc * 32;
        const int buf = kc & 1;
        *(uint4*)&Wsh[buf][nr0 * 32 + p0 * 8] = rh0;
        *(uint4*)&Wsl[buf][nr0 * 32 + p0 * 8] = rl0;
        if (two) {
            *(uint4*)&Wsh[buf][nr1 * 32 + p0 * 8] = rh1;
            *(uint4*)&Wsl[buf][nr1 * 32 + p0 * 8] = rl1;
        }
        if (kc < 6) {
            rh0 = *(const uint4*)&Wth[nr0 * 224 + (k0 + 32) + p0 * 8];
            rl0 = *(const uint4*)&Wtl[nr0 * 224 + (k0 + 32) + p0 * 8];
            if (two) {
                rh1 = *(const uint4*)&Wth[nr1 * 224 + (k0 + 32) + p0 * 8];
                rl1 = *(const uint4*)&Wtl[nr1 * 224 + (k0 + 32) + p0 * 8];
            }
        }
        __syncthreads();
        v8h ah, al;
        int kb = k0 + quad * 8;
        if (kb < 200) {
            v8h ph = pch[kc];
#pragma unroll
            for (int j = 0; j < 8; ++j) {
                float av = (float)ph[j] + bS[kb + j];
                av = LEAKY(av);
                _Float16 h = (_Float16)av;
                ah[j] = h;
                al[j] = (_Float16)(av - (float)h);
            }
        } else {
#pragma unroll
            for (int j = 0; j < 8; ++j) { ah[j] = (_Float16)0.0f; al[j] = (_Float16)0.0f; }
        }
#pragma unroll
        for (int t = 0; t < 13; ++t) {
            int nidx = (t * 16 + l16) * 32 + quad * 8;
            v8h wh = *(const v8h*)&Wsh[buf][nidx];
            v8h wl = *(const v8h*)&Wsl[buf][nidx];
            acc[t] = __builtin_amdgcn_mfma_f32_16x16x32_f16(ah, wh, acc[t], 0, 0, 0);
            acc[t] = __builtin_amdgcn_mfma_f32_16x16x32_f16(ah, wl, acc[t], 0, 0, 0);
            acc[t] = __builtin_amdgcn_mfma_f32_16x16x32_f16(al, wh, acc[t], 0, 0, 0);
        }
    }
    const int rb = blockIdx.x * 128 + wid * 16 + quad * 4;
#pragma unroll
    for (int t = 0; t < 13; ++t) {
        int c = t * 16 + l16;
        if (c < 200) {
#pragma unroll
            for (int e = 0; e < 4; ++e) {
                int r = rb + e;
                if (r < M) T[(size_t)r * 200 + c] = (_Float16)acc[t][e];
            }
        }
    }
}

// ================= propagation (200-wide) via CSR gather, 4-way unrolled edges =================
__global__ __launch_bounds__(256) void k_gather200h(const _Float16* __restrict__ t,
                                                    const float* __restrict__ dinv,
                                                    const int* __restrict__ rowptr,
                                                    const int2* __restrict__ adj,
                                                    _Float16* __restrict__ p, int n) {
    int gid = blockIdx.x * blockDim.x + threadIdx.x;
    if (gid >= n * 25) return;
    int v = gid / 25, c8 = gid - v * 25;
    const v8h* tp = (const v8h*)t;
    float w0 = dinv[v]; w0 *= w0;
    v8h tv = tp[v * 25 + c8];
    float a0[8], a1[8], a2[8], a3[8];
#pragma unroll
    for (int i = 0; i < 8; ++i) { a0[i] = (float)tv[i] * w0; a1[i] = 0.0f; a2[i] = 0.0f; a3[i] = 0.0f; }
    int lo = v ? rowptr[v - 1] : 0;
    int hi = rowptr[v];
    int j = lo;
    for (; j + 3 < hi; j += 4) {
        int2 e0 = adj[j], e1 = adj[j + 1], e2 = adj[j + 2], e3 = adj[j + 3];
        float wa = __int_as_float(e0.y), wb = __int_as_float(e1.y);
        float wc = __int_as_float(e2.y), wd = __int_as_float(e3.y);
        v8h s0 = tp[e0.x * 25 + c8];
        v8h s1 = tp[e1.x * 25 + c8];
        v8h s2 = tp[e2.x * 25 + c8];
        v8h s3 = tp[e3.x * 25 + c8];
#pragma unroll
        for (int i = 0; i < 8; ++i) {
            a0[i] += (float)s0[i] * wa;
            a1[i] += (float)s1[i] * wb;
            a2[i] += (float)s2[i] * wc;
            a3[i] += (float)s3[i] * wd;
        }
    }
    for (; j < hi; ++j) {
        int2 cw = adj[j];
        float w = __int_as_float(cw.y);
        v8h sv = tp[cw.x * 25 + c8];
#pragma unroll
        for (int i = 0; i < 8; ++i) a0[i] += (float)sv[i] * w;
    }
    v8h o;
#pragma unroll
    for (int i = 0; i < 8; ++i) o[i] = (_Float16)((a0[i] + a1[i]) + (a2[i] + a3[i]));
    ((v8h*)p)[v * 25 + c8] = o;
}

// ================= FUSED pooling + head MLP: one block per graph.
// Stream leaky(T+b3) sums -> LDS reduce -> mean+concat -> MLP -> out[g]. =================
__global__ __launch_bounds__(256) void k_poolhead(const _Float16* __restrict__ T,
                                                  const float* __restrict__ b3,
                                                  const int* __restrict__ batch, int n,
                                                  const float* __restrict__ xs,
                                                  const float* __restrict__ Wl1,
                                                  const float* __restrict__ bl1,
                                                  const float* __restrict__ Wl2,
                                                  const float* __restrict__ bl2,
                                                  float* __restrict__ out) {
    __shared__ float part[10][25][9];   // padded inner dim: avoids bank conflicts
    __shared__ float grow[204];
    __shared__ float partial[2];
    __shared__ int sb[2];
    int g = blockIdx.x;
    int t = threadIdx.x;
    if (t == 0 || t == 64) {
        int target = g + (t ? 1 : 0);
        int lo = 0, hi = n;
        while (lo < hi) { int m = (lo + hi) >> 1; if (batch[m] < target) lo = m + 1; else hi = m; }
        sb[t ? 1 : 0] = lo;
    }
    __syncthreads();
    int lo = sb[0], hi = sb[1];
    int c8 = t % 25, li = t / 25;   // 250 active lanes: 25 col-chunks x 10 node-lanes
    if (li < 10) {
        const v8h* tp = (const v8h*)T;
        float4 ba = *(const float4*)(b3 + c8 * 8);
        float4 bb = *(const float4*)(b3 + c8 * 8 + 4);
        float bv[8] = {ba.x, ba.y, ba.z, ba.w, bb.x, bb.y, bb.z, bb.w};
        float acc[8];
#pragma unroll
        for (int i = 0; i < 8; ++i) acc[i] = 0.0f;
        for (int i = lo + li; i < hi; i += 10) {
            v8h tv = tp[(size_t)i * 25 + c8];
#pragma unroll
            for (int jj = 0; jj < 8; ++jj) {
                float v = (float)tv[jj] + bv[jj];
                acc[jj] += LEAKY(v);
            }
        }
#pragma unroll
        for (int jj = 0; jj < 8; ++jj) part[li][c8][jj] = acc[jj];
    }
    __syncthreads();
    if (t < 200) {
        float s = 0.0f;
#pragma unroll
        for (int l2 = 0; l2 < 10; ++l2) s += part[l2][t >> 3][t & 7];
        grow[t] = s / fmaxf((float)(hi - lo), 1.0f);   // col == t
    } else if (t < 204) {
        grow[t] = xs[g * 4 + (t - 200)];
    }
    __syncthreads();
    if (t < 128) {
        float s = bl1[t];
        for (int k = 0; k < 204; ++k) s += grow[k] * Wl1[k * 128 + t];
        s = LEAKY(s);
        float hv = s * Wl2[t];
        for (int off = 32; off > 0; off >>= 1) hv += __shfl_down(hv, off, 64);
        if ((t & 63) == 0) partial[t >> 6] = hv;
    }
    __syncthreads();
    if (t == 0) out[g] = partial[0] + partial[1] + bl2[0];
}

extern "C" void kernel_launch(void* const* d_in, const int* in_sizes, int n_in,
                              void* d_out, int out_size, void* d_ws, size_t ws_size,
                              hipStream_t stream) {
    const float* x    = (const float*)d_in[0];
    const int*   ei   = (const int*)d_in[1];
    const float* xs   = (const float*)d_in[2];
    const int*   batch= (const int*)d_in[3];
    const float* W0   = (const float*)d_in[4];
    const float* b0   = (const float*)d_in[5];
    const float* W1   = (const float*)d_in[6];
    const float* b1   = (const float*)d_in[7];
    const float* W2   = (const float*)d_in[8];
    const float* b2   = (const float*)d_in[9];
    const float* W3   = (const float*)d_in[10];
    const float* b3   = (const float*)d_in[11];
    const float* Wl1  = (const float*)d_in[12];
    const float* bl1  = (const float*)d_in[13];
    const float* Wl2  = (const float*)d_in[14];
    const float* bl2  = (const float*)d_in[15];
    float* out = (float*)d_out;

    const int N = in_sizes[0] / 4;   // 50000 nodes
    const int E = in_sizes[1] / 2;   // 400000 edges
    const int G = in_sizes[2] / 4;   // 500 graphs

    char* ws = (char*)d_ws;
    size_t off = 0;
    auto alloc = [&](size_t bytes) { void* p = ws + off; off += (bytes + 255) & ~size_t(255); return p; };
    _Float16* bufA = (_Float16*)alloc((size_t)N * 200 * sizeof(_Float16)); // GEMM outputs
    _Float16* bufB = (_Float16*)alloc((size_t)N * 200 * sizeof(_Float16)); // gather outputs
    float* dinv   = (float*)alloc((size_t)N * sizeof(float));
    int*   cnt    = (int*)alloc((size_t)N * sizeof(int));
    int*   rowptr = (int*)alloc(((size_t)N + 1) * sizeof(int));
    int*   bsum   = (int*)alloc(256 * sizeof(int));
    int2*  adj    = (int2*)alloc((size_t)E * sizeof(int2));
    _Float16* Wth[3]; _Float16* Wtl[3];
    for (int i = 0; i < 3; ++i) {
        Wth[i] = (_Float16*)alloc(208 * 224 * sizeof(_Float16));
        Wtl[i] = (_Float16*)alloc(208 * 224 * sizeof(_Float16));
    }

    // ---- cooperative prologue (splitW + CSR build, 4 grid syncs) ----
    {
        int Nv = N, Ev = E;
        const float *a0 = W1, *a1 = W2, *a2 = W3;
        _Float16 *p0 = Wth[0], *p1 = Wtl[0], *p2 = Wth[1], *p3 = Wtl[1], *p4 = Wth[2], *p5 = Wtl[2];
        const int* pei = ei;
        int *pcnt = cnt, *prow = rowptr, *pbsum = bsum;
        float* pdinv = dinv;
        int2* padj = adj;
        void* args[] = {&a0, &a1, &a2, &p0, &p1, &p2, &p3, &p4, &p5,
                        &pei, &pcnt, &prow, &pbsum, &pdinv, &padj, &Nv, &Ev};
        hipLaunchCooperativeKernel((void*)k_prol, dim3(512), dim3(256), args, 0, stream);
    }

    const int gblocks = (N * 25 + 255) / 256;
    const int mblocks = (N + 127) / 128;

    // layer 1: GEMM with fused 4-wide gather (A = Ahat x @ W0 + b0 synthesized in-kernel)
    k_gemm200_mfma_l0<<<mblocks, 512, 0, stream>>>(x, dinv, rowptr, adj, W0, b0,
                                                   Wth[0], Wtl[0], bufA, N);
    k_gather200h<<<gblocks, 256, 0, stream>>>(bufA, dinv, rowptr, adj, bufB, N);

    // layers 2-3
    k_gemm200_mfma<<<mblocks, 512, 0, stream>>>(bufB, b1, Wth[1], Wtl[1], bufA, N);
    k_gather200h<<<gblocks, 256, 0, stream>>>(bufA, dinv, rowptr, adj, bufB, N);
    k_gemm200_mfma<<<mblocks, 512, 0, stream>>>(bufB, b2, Wth[2], Wtl[2], bufA, N);
    k_gather200h<<<gblocks, 256, 0, stream>>>(bufA, dinv, rowptr, adj, bufB, N);

    // fused pooling + head MLP (one block per graph)
    k_poolhead<<<G, 256, 0, stream>>>(bufB, b3, batch, N, xs, Wl1, bl1, Wl2, bl2, out);
}

// Round 8
// 345.048 us; speedup vs baseline: 1.6762x; 1.6762x over previous
//
#include <hip/hip_runtime.h>
#include <math.h>

#define LEAKY(v) ((v) > 0.0f ? (v) : 0.01f * (v))

typedef _Float16 v8h __attribute__((ext_vector_type(8)));
typedef float v4f __attribute__((ext_vector_type(4)));

// ================= CSR build =================
__global__ void k_count(const int* __restrict__ ei, int* __restrict__ cnt, int E) {
    int e = blockIdx.x * blockDim.x + threadIdx.x;
    if (e < E) atomicAdd(&cnt[ei[E + e]], 1);
}

// ---- multi-block exclusive scan (scan2 folded into scan3) ----
__global__ __launch_bounds__(256) void k_scan1(const int* __restrict__ cnt,
                                               int* __restrict__ rowptr,
                                               int* __restrict__ bsum, int n) {
    __shared__ int s[256];
    int t = threadIdx.x, i = blockIdx.x * 256 + t;
    int v = (i < n) ? cnt[i] : 0;
    s[t] = v;
    __syncthreads();
    for (int off = 1; off < 256; off <<= 1) {
        int u = (t >= off) ? s[t - off] : 0;
        __syncthreads();
        s[t] += u;
        __syncthreads();
    }
    if (i < n) rowptr[i] = s[t] - v;
    if (t == 255) bsum[blockIdx.x] = s[255];
}

// computes own block-prefix from bsum (nblk<=256 single pass), adds base, computes dinv
__global__ __launch_bounds__(256) void k_scan3(int* __restrict__ rowptr,
                                               const int* __restrict__ bsum,
                                               const int* __restrict__ cnt,
                                               float* __restrict__ dinv, int n) {
    __shared__ int sred[256];
    int t = threadIdx.x;
    int accum = 0;
    for (int b = t; b < (int)blockIdx.x; b += 256) accum += bsum[b];
    sred[t] = accum;
    __syncthreads();
    for (int off = 128; off > 0; off >>= 1) {
        if (t < off) sred[t] += sred[t + off];
        __syncthreads();
    }
    int base = sred[0];
    int i = blockIdx.x * 256 + t;
    if (i < n) {
        rowptr[i] += base;
        dinv[i] = rsqrtf(1.0f + (float)cnt[i]);  // +1 self-loop
    }
}

// atomicAdd directly on rowptr: after this, rowptr[d] = end(d); start(d) = rowptr[d-1].
__global__ void k_fill(const int* __restrict__ ei, const float* __restrict__ dinv,
                       int* __restrict__ rowptr, int2* __restrict__ adj, int E) {
    int e = blockIdx.x * blockDim.x + threadIdx.x;
    if (e < E) {
        int s = ei[e], d = ei[E + e];
        int pos = atomicAdd(&rowptr[d], 1);
        adj[pos] = make_int2(s, __float_as_int(dinv[s] * dinv[d]));
    }
}

// ================= W split (3 layers, one launch) + cnt zero-init (fused; stream order
// guarantees completion before k_count): fp32 [200][200] -> f16 hi/lo [208][224] T
__global__ __launch_bounds__(256) void k_splitW3(const float* __restrict__ W1,
                                                 const float* __restrict__ W2,
                                                 const float* __restrict__ W3,
                                                 _Float16* __restrict__ th0, _Float16* __restrict__ tl0,
                                                 _Float16* __restrict__ th1, _Float16* __restrict__ tl1,
                                                 _Float16* __restrict__ th2, _Float16* __restrict__ tl2,
                                                 int* __restrict__ cnt, int n) {
    int layer = blockIdx.y;
    const float* W = (layer == 0) ? W1 : (layer == 1) ? W2 : W3;
    _Float16* Wth = (layer == 0) ? th0 : (layer == 1) ? th1 : th2;
    _Float16* Wtl = (layer == 0) ? tl0 : (layer == 1) ? tl1 : tl2;
    int idx = blockIdx.x * blockDim.x + threadIdx.x;
    // fused cnt zeroing across the whole grid
    int gidx = (blockIdx.y * gridDim.x + blockIdx.x) * 256 + threadIdx.x;
    for (int j = gidx; j < n; j += gridDim.x * gridDim.y * 256) cnt[j] = 0;
    if (idx >= 224 * 208) return;
    int k = idx / 208, c = idx - k * 208;
    float v = (k < 200 && c < 200) ? W[k * 200 + c] : 0.0f;
    _Float16 hi = (_Float16)v;
    _Float16 lo = (_Float16)(v - (float)hi);
    Wth[c * 224 + k] = hi;
    Wtl[c * 224 + k] = lo;
}

// ================= layer-1 GEMM with FUSED 4-wide gather, 128-row tile,
// reg-staged double-buffered W pipeline (1 barrier per K-step):
// T = leaky((Ahat x)@W0 + b0) @ W1.
__global__ __launch_bounds__(512, 4) void k_gemm200_mfma_l0(const float* __restrict__ x,
                                                            const float* __restrict__ dinv,
                                                            const int* __restrict__ rowptr,
                                                            const int2* __restrict__ adj,
                                                            const float* __restrict__ W0,
                                                            const float* __restrict__ b0,
                                                            const _Float16* __restrict__ Wth,
                                                            const _Float16* __restrict__ Wtl,
                                                            _Float16* __restrict__ T, int M) {
    __shared__ _Float16 Wsh[2][208 * 32];
    __shared__ _Float16 Wsl[2][208 * 32];
    __shared__ float W0s[4][200];
    __shared__ float b0s[200];
    const int tid  = threadIdx.x;
    const int lane = tid & 63;
    const int wid  = tid >> 6;       // 0..7
    const int quad = lane >> 4;
    const int l16  = lane & 15;
    const int rowA = blockIdx.x * 128 + wid * 16 + l16;
    const int rowAc = min(rowA, M - 1);

    // W stage-reg geometry: 832 uint4 per half-tile over 512 threads
    const int nr0 = tid >> 2, p0 = tid & 3;
    const bool two = (tid < 320);
    const int nr1 = nr0 + 128;
    uint4 rh0, rl0, rh1, rl1;
    // issue k0=0 W loads FIRST (latency hides under gather + W0 staging)
    rh0 = *(const uint4*)&Wth[nr0 * 224 + p0 * 8];
    rl0 = *(const uint4*)&Wtl[nr0 * 224 + p0 * 8];
    if (two) {
        rh1 = *(const uint4*)&Wth[nr1 * 224 + p0 * 8];
        rl1 = *(const uint4*)&Wtl[nr1 * 224 + p0 * 8];
    }

    // stage W0/b0 (read after first barrier)
    for (int idx = tid; idx < 1000; idx += 512) {
        if (idx < 800) W0s[idx / 200][idx % 200] = W0[idx];
        else b0s[idx - 800] = b0[idx - 800];
    }

    // ---- fused gather4 ----
    float w0n = dinv[rowAc]; w0n *= w0n;
    float4 xv = ((const float4*)x)[rowAc];
    float4 pxv = make_float4(xv.x * w0n, xv.y * w0n, xv.z * w0n, xv.w * w0n);
    {
        int lo = rowAc ? rowptr[rowAc - 1] : 0;
        int hi = rowptr[rowAc];
        for (int j = lo; j < hi; ++j) {
            int2 cw = adj[j];
            float w = __int_as_float(cw.y);
            float4 sv = ((const float4*)x)[cw.x];
            pxv.x += sv.x * w; pxv.y += sv.y * w; pxv.z += sv.z * w; pxv.w += sv.w * w;
        }
    }

    v4f acc[13];
#pragma unroll
    for (int t = 0; t < 13; ++t) acc[t] = 0.0f;

#pragma unroll
    for (int kc = 0; kc < 7; ++kc) {
        const int k0 = kc * 32;
        const int buf = kc & 1;
        // write staged regs -> LDS[buf] (prev iter's MFMA read buf^1: no WAR)
        *(uint4*)&Wsh[buf][nr0 * 32 + p0 * 8] = rh0;
        *(uint4*)&Wsl[buf][nr0 * 32 + p0 * 8] = rl0;
        if (two) {
            *(uint4*)&Wsh[buf][nr1 * 32 + p0 * 8] = rh1;
            *(uint4*)&Wsl[buf][nr1 * 32 + p0 * 8] = rl1;
        }
        // issue next K-step's W loads (latency hides under MFMA below)
        if (kc < 6) {
            rh0 = *(const uint4*)&Wth[nr0 * 224 + (k0 + 32) + p0 * 8];
            rl0 = *(const uint4*)&Wtl[nr0 * 224 + (k0 + 32) + p0 * 8];
            if (two) {
                rh1 = *(const uint4*)&Wth[nr1 * 224 + (k0 + 32) + p0 * 8];
                rl1 = *(const uint4*)&Wtl[nr1 * 224 + (k0 + 32) + p0 * 8];
            }
        }
        __syncthreads();
        // A fragment (VALU, from registers + staged W0s)
        v8h ah, al;
        int kb = k0 + quad * 8;
        if (kb < 200) {
#pragma unroll
            for (int j = 0; j < 8; ++j) {
                int k = kb + j;
                float pv = pxv.x * W0s[0][k] + pxv.y * W0s[1][k]
                         + pxv.z * W0s[2][k] + pxv.w * W0s[3][k] + b0s[k];
                pv = LEAKY(pv);
                _Float16 h = (_Float16)pv;
                ah[j] = h;
                al[j] = (_Float16)(pv - (float)h);
            }
        } else {
#pragma unroll
            for (int j = 0; j < 8; ++j) { ah[j] = (_Float16)0.0f; al[j] = (_Float16)0.0f; }
        }
#pragma unroll
        for (int t = 0; t < 13; ++t) {
            int nidx = (t * 16 + l16) * 32 + quad * 8;
            v8h wh = *(const v8h*)&Wsh[buf][nidx];
            v8h wl = *(const v8h*)&Wsl[buf][nidx];
            acc[t] = __builtin_amdgcn_mfma_f32_16x16x32_f16(ah, wh, acc[t], 0, 0, 0);
            acc[t] = __builtin_amdgcn_mfma_f32_16x16x32_f16(ah, wl, acc[t], 0, 0, 0);
            acc[t] = __builtin_amdgcn_mfma_f32_16x16x32_f16(al, wh, acc[t], 0, 0, 0);
        }
    }
    const int rb = blockIdx.x * 128 + wid * 16 + quad * 4;
#pragma unroll
    for (int t = 0; t < 13; ++t) {
        int c = t * 16 + l16;
        if (c < 200) {
#pragma unroll
            for (int e = 0; e < 4; ++e) {
                int r = rb + e;
                if (r < M) T[(size_t)r * 200 + c] = (_Float16)acc[t][e];
            }
        }
    }
}

// ================= layers 2-3 GEMM, 128-row tile, A-prefetch + pipelined W:
// T = leaky(P + bprev) @ W =================
__global__ __launch_bounds__(512, 4) void k_gemm200_mfma(const _Float16* __restrict__ P,
                                                         const float* __restrict__ bias,
                                                         const _Float16* __restrict__ Wth,
                                                         const _Float16* __restrict__ Wtl,
                                                         _Float16* __restrict__ T, int M) {
    __shared__ _Float16 Wsh[2][208 * 32];
    __shared__ _Float16 Wsl[2][208 * 32];
    __shared__ float bS[200];
    const int tid  = threadIdx.x;
    const int lane = tid & 63;
    const int wid  = tid >> 6;       // 0..7
    const int quad = lane >> 4;
    const int l16  = lane & 15;
    const int rowA = blockIdx.x * 128 + wid * 16 + l16;
    const int rowAc = min(rowA, M - 1);
    const _Float16* Prow = P + (size_t)rowAc * 200;

    const int nr0 = tid >> 2, p0 = tid & 3;
    const bool two = (tid < 320);
    const int nr1 = nr0 + 128;
    uint4 rh0, rl0, rh1, rl1;
    rh0 = *(const uint4*)&Wth[nr0 * 224 + p0 * 8];
    rl0 = *(const uint4*)&Wtl[nr0 * 224 + p0 * 8];
    if (two) {
        rh1 = *(const uint4*)&Wth[nr1 * 224 + p0 * 8];
        rl1 = *(const uint4*)&Wtl[nr1 * 224 + p0 * 8];
    }
    if (tid < 200) bS[tid] = bias[tid];

    // prefetch ALL A chunks (7 independent loads, one latency)
    v8h pch[7];
#pragma unroll
    for (int kc = 0; kc < 7; ++kc) {
        int kb = kc * 32 + quad * 8;
        if (kb < 200) {
            pch[kc] = *(const v8h*)(Prow + kb);
        } else {
#pragma unroll
            for (int j = 0; j < 8; ++j) pch[kc][j] = (_Float16)0.0f;
        }
    }

    v4f acc[13];
#pragma unroll
    for (int t = 0; t < 13; ++t) acc[t] = 0.0f;

#pragma unroll
    for (int kc = 0; kc < 7; ++kc) {
        const int k0 = kc * 32;
        const int buf = kc & 1;
        *(uint4*)&Wsh[buf][nr0 * 32 + p0 * 8] = rh0;
        *(uint4*)&Wsl[buf][nr0 * 32 + p0 * 8] = rl0;
        if (two) {
            *(uint4*)&Wsh[buf][nr1 * 32 + p0 * 8] = rh1;
            *(uint4*)&Wsl[buf][nr1 * 32 + p0 * 8] = rl1;
        }
        if (kc < 6) {
            rh0 = *(const uint4*)&Wth[nr0 * 224 + (k0 + 32) + p0 * 8];
            rl0 = *(const uint4*)&Wtl[nr0 * 224 + (k0 + 32) + p0 * 8];
            if (two) {
                rh1 = *(const uint4*)&Wth[nr1 * 224 + (k0 + 32) + p0 * 8];
                rl1 = *(const uint4*)&Wtl[nr1 * 224 + (k0 + 32) + p0 * 8];
            }
        }
        __syncthreads();
        v8h ah, al;
        int kb = k0 + quad * 8;
        if (kb < 200) {
            v8h ph = pch[kc];
#pragma unroll
            for (int j = 0; j < 8; ++j) {
                float av = (float)ph[j] + bS[kb + j];
                av = LEAKY(av);
                _Float16 h = (_Float16)av;
                ah[j] = h;
                al[j] = (_Float16)(av - (float)h);
            }
        } else {
#pragma unroll
            for (int j = 0; j < 8; ++j) { ah[j] = (_Float16)0.0f; al[j] = (_Float16)0.0f; }
        }
#pragma unroll
        for (int t = 0; t < 13; ++t) {
            int nidx = (t * 16 + l16) * 32 + quad * 8;
            v8h wh = *(const v8h*)&Wsh[buf][nidx];
            v8h wl = *(const v8h*)&Wsl[buf][nidx];
            acc[t] = __builtin_amdgcn_mfma_f32_16x16x32_f16(ah, wh, acc[t], 0, 0, 0);
            acc[t] = __builtin_amdgcn_mfma_f32_16x16x32_f16(ah, wl, acc[t], 0, 0, 0);
            acc[t] = __builtin_amdgcn_mfma_f32_16x16x32_f16(al, wh, acc[t], 0, 0, 0);
        }
    }
    const int rb = blockIdx.x * 128 + wid * 16 + quad * 4;
#pragma unroll
    for (int t = 0; t < 13; ++t) {
        int c = t * 16 + l16;
        if (c < 200) {
#pragma unroll
            for (int e = 0; e < 4; ++e) {
                int r = rb + e;
                if (r < M) T[(size_t)r * 200 + c] = (_Float16)acc[t][e];
            }
        }
    }
}

// ================= propagation (200-wide) via CSR gather, 2 chunks/thread,
// 2-way edge unroll (halves adj/rowptr traffic, 6 loads in flight) =================
__global__ __launch_bounds__(256) void k_gather200h(const _Float16* __restrict__ t,
                                                    const float* __restrict__ dinv,
                                                    const int* __restrict__ rowptr,
                                                    const int2* __restrict__ adj,
                                                    _Float16* __restrict__ p, int n) {
    int gid = blockIdx.x * blockDim.x + threadIdx.x;
    if (gid >= n * 13) return;
    int v = gid / 13, ci = gid - v * 13;
    int c8a = ci * 2;
    int c8b = c8a + 1;
    const bool hb = (c8b < 25);
    const v8h* tp = (const v8h*)t;
    float w0 = dinv[v]; w0 *= w0;
    const int rowbase = v * 25;
    v8h ta = tp[rowbase + c8a];
    v8h tb = hb ? tp[rowbase + c8b] : ta;
    float a0a[8], a1a[8], a0b[8], a1b[8];
#pragma unroll
    for (int i = 0; i < 8; ++i) {
        a0a[i] = (float)ta[i] * w0; a1a[i] = 0.0f;
        a0b[i] = (float)tb[i] * w0; a1b[i] = 0.0f;
    }
    int lo = v ? rowptr[v - 1] : 0;
    int hi = rowptr[v];
    int j = lo;
    for (; j + 1 < hi; j += 2) {
        int2 e0 = adj[j], e1 = adj[j + 1];
        float wa = __int_as_float(e0.y), wb = __int_as_float(e1.y);
        int b0 = e0.x * 25, b1 = e1.x * 25;
        v8h s0a = tp[b0 + c8a];
        v8h s1a = tp[b1 + c8a];
        v8h s0b = hb ? tp[b0 + c8b] : s0a;
        v8h s1b = hb ? tp[b1 + c8b] : s1a;
#pragma unroll
        for (int i = 0; i < 8; ++i) {
            a0a[i] += (float)s0a[i] * wa;
            a1a[i] += (float)s1a[i] * wb;
            a0b[i] += (float)s0b[i] * wa;
            a1b[i] += (float)s1b[i] * wb;
        }
    }
    if (j < hi) {
        int2 cw = adj[j];
        float w = __int_as_float(cw.y);
        int b0 = cw.x * 25;
        v8h sva = tp[b0 + c8a];
        v8h svb = hb ? tp[b0 + c8b] : sva;
#pragma unroll
        for (int i = 0; i < 8; ++i) {
            a0a[i] += (float)sva[i] * w;
            a0b[i] += (float)svb[i] * w;
        }
    }
    v8h oa, ob;
#pragma unroll
    for (int i = 0; i < 8; ++i) {
        oa[i] = (_Float16)(a0a[i] + a1a[i]);
        ob[i] = (_Float16)(a0b[i] + a1b[i]);
    }
    ((v8h*)p)[rowbase + c8a] = oa;
    if (hb) ((v8h*)p)[rowbase + c8b] = ob;
}

// ================= FUSED pooling + head MLP: one block per graph.
// Stream leaky(T+b3) sums -> LDS reduce -> mean+concat -> MLP -> out[g]. =================
__global__ __launch_bounds__(256) void k_poolhead(const _Float16* __restrict__ T,
                                                  const float* __restrict__ b3,
                                                  const int* __restrict__ batch, int n,
                                                  const float* __restrict__ xs,
                                                  const float* __restrict__ Wl1,
                                                  const float* __restrict__ bl1,
                                                  const float* __restrict__ Wl2,
                                                  const float* __restrict__ bl2,
                                                  float* __restrict__ out) {
    __shared__ float part[10][25][9];   // padded inner dim: avoids bank conflicts
    __shared__ float grow[204];
    __shared__ float partial[2];
    __shared__ int sb[2];
    int g = blockIdx.x;
    int t = threadIdx.x;
    if (t == 0 || t == 64) {
        int target = g + (t ? 1 : 0);
        int lo = 0, hi = n;
        while (lo < hi) { int m = (lo + hi) >> 1; if (batch[m] < target) lo = m + 1; else hi = m; }
        sb[t ? 1 : 0] = lo;
    }
    __syncthreads();
    int lo = sb[0], hi = sb[1];
    int c8 = t % 25, li = t / 25;   // 250 active lanes: 25 col-chunks x 10 node-lanes
    if (li < 10) {
        const v8h* tp = (const v8h*)T;
        float4 ba = *(const float4*)(b3 + c8 * 8);
        float4 bb = *(const float4*)(b3 + c8 * 8 + 4);
        float bv[8] = {ba.x, ba.y, ba.z, ba.w, bb.x, bb.y, bb.z, bb.w};
        float acc[8];
#pragma unroll
        for (int i = 0; i < 8; ++i) acc[i] = 0.0f;
        for (int i = lo + li; i < hi; i += 10) {
            v8h tv = tp[(size_t)i * 25 + c8];
#pragma unroll
            for (int jj = 0; jj < 8; ++jj) {
                float v = (float)tv[jj] + bv[jj];
                acc[jj] += LEAKY(v);
            }
        }
#pragma unroll
        for (int jj = 0; jj < 8; ++jj) part[li][c8][jj] = acc[jj];
    }
    __syncthreads();
    if (t < 200) {
        float s = 0.0f;
#pragma unroll
        for (int l2 = 0; l2 < 10; ++l2) s += part[l2][t >> 3][t & 7];
        grow[t] = s / fmaxf((float)(hi - lo), 1.0f);   // col == t
    } else if (t < 204) {
        grow[t] = xs[g * 4 + (t - 200)];
    }
    __syncthreads();
    if (t < 128) {
        float s = bl1[t];
        for (int k = 0; k < 204; ++k) s += grow[k] * Wl1[k * 128 + t];
        s = LEAKY(s);
        float hv = s * Wl2[t];
        for (int off = 32; off > 0; off >>= 1) hv += __shfl_down(hv, off, 64);
        if ((t & 63) == 0) partial[t >> 6] = hv;
    }
    __syncthreads();
    if (t == 0) out[g] = partial[0] + partial[1] + bl2[0];
}

extern "C" void kernel_launch(void* const* d_in, const int* in_sizes, int n_in,
                              void* d_out, int out_size, void* d_ws, size_t ws_size,
                              hipStream_t stream) {
    const float* x    = (const float*)d_in[0];
    const int*   ei   = (const int*)d_in[1];
    const float* xs   = (const float*)d_in[2];
    const int*   batch= (const int*)d_in[3];
    const float* W0   = (const float*)d_in[4];
    const float* b0   = (const float*)d_in[5];
    const float* W1   = (const float*)d_in[6];
    const float* b1   = (const float*)d_in[7];
    const float* W2   = (const float*)d_in[8];
    const float* b2   = (const float*)d_in[9];
    const float* W3   = (const float*)d_in[10];
    const float* b3   = (const float*)d_in[11];
    const float* Wl1  = (const float*)d_in[12];
    const float* bl1  = (const float*)d_in[13];
    const float* Wl2  = (const float*)d_in[14];
    const float* bl2  = (const float*)d_in[15];
    float* out = (float*)d_out;

    const int N = in_sizes[0] / 4;   // 50000 nodes
    const int E = in_sizes[1] / 2;   // 400000 edges
    const int G = in_sizes[2] / 4;   // 500 graphs

    char* ws = (char*)d_ws;
    size_t off = 0;
    auto alloc = [&](size_t bytes) { void* p = ws + off; off += (bytes + 255) & ~size_t(255); return p; };
    _Float16* bufA = (_Float16*)alloc((size_t)N * 200 * sizeof(_Float16)); // GEMM outputs
    _Float16* bufB = (_Float16*)alloc((size_t)N * 200 * sizeof(_Float16)); // gather outputs
    float* dinv   = (float*)alloc((size_t)N * sizeof(float));
    int*   cnt    = (int*)alloc((size_t)N * sizeof(int));
    int*   rowptr = (int*)alloc(((size_t)N + 1) * sizeof(int));
    int*   bsum   = (int*)alloc(256 * sizeof(int));
    int2*  adj    = (int2*)alloc((size_t)E * sizeof(int2));
    _Float16* Wth[3]; _Float16* Wtl[3];
    for (int i = 0; i < 3; ++i) {
        Wth[i] = (_Float16*)alloc(208 * 224 * sizeof(_Float16));
        Wtl[i] = (_Float16*)alloc(208 * 224 * sizeof(_Float16));
    }

    const int B = 256;
    const int nblk = (N + 255) / 256;

    // W splits (3 layers, one launch) + cnt zeroing (fused; must precede k_count)
    dim3 sg((224 * 208 + B - 1) / B, 3);
    k_splitW3<<<sg, B, 0, stream>>>(W1, W2, W3, Wth[0], Wtl[0], Wth[1], Wtl[1], Wth[2], Wtl[2],
                                    cnt, N);

    // CSR build (by destination) + norms; fill uses shifted rowptr convention
    k_count<<<(E + B - 1) / B, B, 0, stream>>>(ei, cnt, E);
    k_scan1<<<nblk, 256, 0, stream>>>(cnt, rowptr, bsum, N);
    k_scan3<<<nblk, 256, 0, stream>>>(rowptr, bsum, cnt, dinv, N);
    k_fill<<<(E + B - 1) / B, B, 0, stream>>>(ei, dinv, rowptr, adj, E);

    const int gblocks = (N * 13 + 255) / 256;
    const int mblocks = (N + 127) / 128;

    // layer 1: GEMM with fused 4-wide gather (A = Ahat x @ W0 + b0 synthesized in-kernel)
    k_gemm200_mfma_l0<<<mblocks, 512, 0, stream>>>(x, dinv, rowptr, adj, W0, b0,
                                                   Wth[0], Wtl[0], bufA, N);
    k_gather200h<<<gblocks, 256, 0, stream>>>(bufA, dinv, rowptr, adj, bufB, N);

    // layers 2-3
    k_gemm200_mfma<<<mblocks, 512, 0, stream>>>(bufB, b1, Wth[1], Wtl[1], bufA, N);
    k_gather200h<<<gblocks, 256, 0, stream>>>(bufA, dinv, rowptr, adj, bufB, N);
    k_gemm200_mfma<<<mblocks, 512, 0, stream>>>(bufB, b2, Wth[2], Wtl[2], bufA, N);
    k_gather200h<<<gblocks, 256, 0, stream>>>(bufA, dinv, rowptr, adj, bufB, N);

    // fused pooling + head MLP (one block per graph)
    k_poolhead<<<G, 256, 0, stream>>>(bufB, b3, batch, N, xs, Wl1, bl1, Wl2, bl2, out);
}

// Round 9
// 327.596 us; speedup vs baseline: 1.7655x; 1.0533x over previous
//
#include <hip/hip_runtime.h>
#include <math.h>

#define LEAKY(v) ((v) > 0.0f ? (v) : 0.01f * (v))

typedef _Float16 v8h __attribute__((ext_vector_type(8)));
typedef float v4f __attribute__((ext_vector_type(4)));

// ================= CSR build =================
__global__ void k_count(const int* __restrict__ ei, int* __restrict__ cnt, int E) {
    int e = blockIdx.x * blockDim.x + threadIdx.x;
    if (e < E) atomicAdd(&cnt[ei[E + e]], 1);
}

// ---- multi-block exclusive scan (scan2 folded into scan3) ----
__global__ __launch_bounds__(256) void k_scan1(const int* __restrict__ cnt,
                                               int* __restrict__ rowptr,
                                               int* __restrict__ bsum, int n) {
    __shared__ int s[256];
    int t = threadIdx.x, i = blockIdx.x * 256 + t;
    int v = (i < n) ? cnt[i] : 0;
    s[t] = v;
    __syncthreads();
    for (int off = 1; off < 256; off <<= 1) {
        int u = (t >= off) ? s[t - off] : 0;
        __syncthreads();
        s[t] += u;
        __syncthreads();
    }
    if (i < n) rowptr[i] = s[t] - v;
    if (t == 255) bsum[blockIdx.x] = s[255];
}

// computes own block-prefix from bsum, adds base, computes dinv, zeroes pooled (fused)
__global__ __launch_bounds__(256) void k_scan3(int* __restrict__ rowptr,
                                               const int* __restrict__ bsum,
                                               const int* __restrict__ cnt,
                                               float* __restrict__ dinv, int n,
                                               float* __restrict__ pooled, int npool) {
    __shared__ int sred[256];
    int t = threadIdx.x;
    int accum = 0;
    for (int b = t; b < (int)blockIdx.x; b += 256) accum += bsum[b];
    sred[t] = accum;
    __syncthreads();
    for (int off = 128; off > 0; off >>= 1) {
        if (t < off) sred[t] += sred[t + off];
        __syncthreads();
    }
    int base = sred[0];
    int i = blockIdx.x * 256 + t;
    if (i < n) {
        rowptr[i] += base;
        dinv[i] = rsqrtf(1.0f + (float)cnt[i]);  // +1 self-loop
    }
    for (int j = i; j < npool; j += gridDim.x * 256) pooled[j] = 0.0f;
}

// atomicAdd directly on rowptr: after this, rowptr[d] = end(d); start(d) = rowptr[d-1].
__global__ void k_fill(const int* __restrict__ ei, const float* __restrict__ dinv,
                       int* __restrict__ rowptr, int2* __restrict__ adj, int E) {
    int e = blockIdx.x * blockDim.x + threadIdx.x;
    if (e < E) {
        int s = ei[e], d = ei[E + e];
        int pos = atomicAdd(&rowptr[d], 1);
        adj[pos] = make_int2(s, __float_as_int(dinv[s] * dinv[d]));
    }
}

// ================= W split (3 layers, one launch) + cnt zero-init (fused; stream order
// guarantees completion before k_count): fp32 [200][200] -> f16 hi/lo [208][224] T
__global__ __launch_bounds__(256) void k_splitW3(const float* __restrict__ W1,
                                                 const float* __restrict__ W2,
                                                 const float* __restrict__ W3,
                                                 _Float16* __restrict__ th0, _Float16* __restrict__ tl0,
                                                 _Float16* __restrict__ th1, _Float16* __restrict__ tl1,
                                                 _Float16* __restrict__ th2, _Float16* __restrict__ tl2,
                                                 int* __restrict__ cnt, int n) {
    int layer = blockIdx.y;
    const float* W = (layer == 0) ? W1 : (layer == 1) ? W2 : W3;
    _Float16* Wth = (layer == 0) ? th0 : (layer == 1) ? th1 : th2;
    _Float16* Wtl = (layer == 0) ? tl0 : (layer == 1) ? tl1 : tl2;
    int idx = blockIdx.x * blockDim.x + threadIdx.x;
    // fused cnt zeroing across the whole grid
    int gidx = (blockIdx.y * gridDim.x + blockIdx.x) * 256 + threadIdx.x;
    for (int j = gidx; j < n; j += gridDim.x * gridDim.y * 256) cnt[j] = 0;
    if (idx >= 224 * 208) return;
    int k = idx / 208, c = idx - k * 208;
    float v = (k < 200 && c < 200) ? W[k * 200 + c] : 0.0f;
    _Float16 hi = (_Float16)v;
    _Float16 lo = (_Float16)(v - (float)hi);
    Wth[c * 224 + k] = hi;
    Wtl[c * 224 + k] = lo;
}

// ================= layer-1 GEMM with FUSED 4-wide gather, 128-row tile,
// reg-staged double-buffered W pipeline (1 barrier per K-step):
// T = leaky((Ahat x)@W0 + b0) @ W1.
__global__ __launch_bounds__(512, 4) void k_gemm200_mfma_l0(const float* __restrict__ x,
                                                            const float* __restrict__ dinv,
                                                            const int* __restrict__ rowptr,
                                                            const int2* __restrict__ adj,
                                                            const float* __restrict__ W0,
                                                            const float* __restrict__ b0,
                                                            const _Float16* __restrict__ Wth,
                                                            const _Float16* __restrict__ Wtl,
                                                            _Float16* __restrict__ T, int M) {
    __shared__ _Float16 Wsh[2][208 * 32];
    __shared__ _Float16 Wsl[2][208 * 32];
    __shared__ float W0s[4][200];
    __shared__ float b0s[200];
    const int tid  = threadIdx.x;
    const int lane = tid & 63;
    const int wid  = tid >> 6;       // 0..7
    const int quad = lane >> 4;
    const int l16  = lane & 15;
    const int rowA = blockIdx.x * 128 + wid * 16 + l16;
    const int rowAc = min(rowA, M - 1);

    // W stage-reg geometry: 832 uint4 per half-tile over 512 threads
    const int nr0 = tid >> 2, p0 = tid & 3;
    const bool two = (tid < 320);
    const int nr1 = nr0 + 128;
    uint4 rh0, rl0, rh1, rl1;
    // issue k0=0 W loads FIRST (latency hides under gather + W0 staging)
    rh0 = *(const uint4*)&Wth[nr0 * 224 + p0 * 8];
    rl0 = *(const uint4*)&Wtl[nr0 * 224 + p0 * 8];
    if (two) {
        rh1 = *(const uint4*)&Wth[nr1 * 224 + p0 * 8];
        rl1 = *(const uint4*)&Wtl[nr1 * 224 + p0 * 8];
    }

    // stage W0/b0 (read after first barrier)
    for (int idx = tid; idx < 1000; idx += 512) {
        if (idx < 800) W0s[idx / 200][idx % 200] = W0[idx];
        else b0s[idx - 800] = b0[idx - 800];
    }

    // ---- fused gather4 ----
    float w0n = dinv[rowAc]; w0n *= w0n;
    float4 xv = ((const float4*)x)[rowAc];
    float4 pxv = make_float4(xv.x * w0n, xv.y * w0n, xv.z * w0n, xv.w * w0n);
    {
        int lo = rowAc ? rowptr[rowAc - 1] : 0;
        int hi = rowptr[rowAc];
        for (int j = lo; j < hi; ++j) {
            int2 cw = adj[j];
            float w = __int_as_float(cw.y);
            float4 sv = ((const float4*)x)[cw.x];
            pxv.x += sv.x * w; pxv.y += sv.y * w; pxv.z += sv.z * w; pxv.w += sv.w * w;
        }
    }

    v4f acc[13];
#pragma unroll
    for (int t = 0; t < 13; ++t) acc[t] = 0.0f;

#pragma unroll
    for (int kc = 0; kc < 7; ++kc) {
        const int k0 = kc * 32;
        const int buf = kc & 1;
        // write staged regs -> LDS[buf] (prev iter's MFMA read buf^1: no WAR)
        *(uint4*)&Wsh[buf][nr0 * 32 + p0 * 8] = rh0;
        *(uint4*)&Wsl[buf][nr0 * 32 + p0 * 8] = rl0;
        if (two) {
            *(uint4*)&Wsh[buf][nr1 * 32 + p0 * 8] = rh1;
            *(uint4*)&Wsl[buf][nr1 * 32 + p0 * 8] = rl1;
        }
        // issue next K-step's W loads (latency hides under MFMA below)
        if (kc < 6) {
            rh0 = *(const uint4*)&Wth[nr0 * 224 + (k0 + 32) + p0 * 8];
            rl0 = *(const uint4*)&Wtl[nr0 * 224 + (k0 + 32) + p0 * 8];
            if (two) {
                rh1 = *(const uint4*)&Wth[nr1 * 224 + (k0 + 32) + p0 * 8];
                rl1 = *(const uint4*)&Wtl[nr1 * 224 + (k0 + 32) + p0 * 8];
            }
        }
        __syncthreads();
        // A fragment (VALU, from registers + staged W0s)
        v8h ah, al;
        int kb = k0 + quad * 8;
        if (kb < 200) {
#pragma unroll
            for (int j = 0; j < 8; ++j) {
                int k = kb + j;
                float pv = pxv.x * W0s[0][k] + pxv.y * W0s[1][k]
                         + pxv.z * W0s[2][k] + pxv.w * W0s[3][k] + b0s[k];
                pv = LEAKY(pv);
                _Float16 h = (_Float16)pv;
                ah[j] = h;
                al[j] = (_Float16)(pv - (float)h);
            }
        } else {
#pragma unroll
            for (int j = 0; j < 8; ++j) { ah[j] = (_Float16)0.0f; al[j] = (_Float16)0.0f; }
        }
#pragma unroll
        for (int t = 0; t < 13; ++t) {
            int nidx = (t * 16 + l16) * 32 + quad * 8;
            v8h wh = *(const v8h*)&Wsh[buf][nidx];
            v8h wl = *(const v8h*)&Wsl[buf][nidx];
            acc[t] = __builtin_amdgcn_mfma_f32_16x16x32_f16(ah, wh, acc[t], 0, 0, 0);
            acc[t] = __builtin_amdgcn_mfma_f32_16x16x32_f16(ah, wl, acc[t], 0, 0, 0);
            acc[t] = __builtin_amdgcn_mfma_f32_16x16x32_f16(al, wh, acc[t], 0, 0, 0);
        }
    }
    const int rb = blockIdx.x * 128 + wid * 16 + quad * 4;
#pragma unroll
    for (int t = 0; t < 13; ++t) {
        int c = t * 16 + l16;
        if (c < 200) {
#pragma unroll
            for (int e = 0; e < 4; ++e) {
                int r = rb + e;
                if (r < M) T[(size_t)r * 200 + c] = (_Float16)acc[t][e];
            }
        }
    }
}

// ================= layers 2-3 GEMM, 128-row tile, A-prefetch + pipelined W:
// T = leaky(P + bprev) @ W =================
__global__ __launch_bounds__(512, 4) void k_gemm200_mfma(const _Float16* __restrict__ P,
                                                         const float* __restrict__ bias,
                                                         const _Float16* __restrict__ Wth,
                                                         const _Float16* __restrict__ Wtl,
                                                         _Float16* __restrict__ T, int M) {
    __shared__ _Float16 Wsh[2][208 * 32];
    __shared__ _Float16 Wsl[2][208 * 32];
    __shared__ float bS[200];
    const int tid  = threadIdx.x;
    const int lane = tid & 63;
    const int wid  = tid >> 6;       // 0..7
    const int quad = lane >> 4;
    const int l16  = lane & 15;
    const int rowA = blockIdx.x * 128 + wid * 16 + l16;
    const int rowAc = min(rowA, M - 1);
    const _Float16* Prow = P + (size_t)rowAc * 200;

    const int nr0 = tid >> 2, p0 = tid & 3;
    const bool two = (tid < 320);
    const int nr1 = nr0 + 128;
    uint4 rh0, rl0, rh1, rl1;
    rh0 = *(const uint4*)&Wth[nr0 * 224 + p0 * 8];
    rl0 = *(const uint4*)&Wtl[nr0 * 224 + p0 * 8];
    if (two) {
        rh1 = *(const uint4*)&Wth[nr1 * 224 + p0 * 8];
        rl1 = *(const uint4*)&Wtl[nr1 * 224 + p0 * 8];
    }
    if (tid < 200) bS[tid] = bias[tid];

    // prefetch ALL A chunks (7 independent loads, one latency)
    v8h pch[7];
#pragma unroll
    for (int kc = 0; kc < 7; ++kc) {
        int kb = kc * 32 + quad * 8;
        if (kb < 200) {
            pch[kc] = *(const v8h*)(Prow + kb);
        } else {
#pragma unroll
            for (int j = 0; j < 8; ++j) pch[kc][j] = (_Float16)0.0f;
        }
    }

    v4f acc[13];
#pragma unroll
    for (int t = 0; t < 13; ++t) acc[t] = 0.0f;

#pragma unroll
    for (int kc = 0; kc < 7; ++kc) {
        const int k0 = kc * 32;
        const int buf = kc & 1;
        *(uint4*)&Wsh[buf][nr0 * 32 + p0 * 8] = rh0;
        *(uint4*)&Wsl[buf][nr0 * 32 + p0 * 8] = rl0;
        if (two) {
            *(uint4*)&Wsh[buf][nr1 * 32 + p0 * 8] = rh1;
            *(uint4*)&Wsl[buf][nr1 * 32 + p0 * 8] = rl1;
        }
        if (kc < 6) {
            rh0 = *(const uint4*)&Wth[nr0 * 224 + (k0 + 32) + p0 * 8];
            rl0 = *(const uint4*)&Wtl[nr0 * 224 + (k0 + 32) + p0 * 8];
            if (two) {
                rh1 = *(const uint4*)&Wth[nr1 * 224 + (k0 + 32) + p0 * 8];
                rl1 = *(const uint4*)&Wtl[nr1 * 224 + (k0 + 32) + p0 * 8];
            }
        }
        __syncthreads();
        v8h ah, al;
        int kb = k0 + quad * 8;
        if (kb < 200) {
            v8h ph = pch[kc];
#pragma unroll
            for (int j = 0; j < 8; ++j) {
                float av = (float)ph[j] + bS[kb + j];
                av = LEAKY(av);
                _Float16 h = (_Float16)av;
                ah[j] = h;
                al[j] = (_Float16)(av - (float)h);
            }
        } else {
#pragma unroll
            for (int j = 0; j < 8; ++j) { ah[j] = (_Float16)0.0f; al[j] = (_Float16)0.0f; }
        }
#pragma unroll
        for (int t = 0; t < 13; ++t) {
            int nidx = (t * 16 + l16) * 32 + quad * 8;
            v8h wh = *(const v8h*)&Wsh[buf][nidx];
            v8h wl = *(const v8h*)&Wsl[buf][nidx];
            acc[t] = __builtin_amdgcn_mfma_f32_16x16x32_f16(ah, wh, acc[t], 0, 0, 0);
            acc[t] = __builtin_amdgcn_mfma_f32_16x16x32_f16(ah, wl, acc[t], 0, 0, 0);
            acc[t] = __builtin_amdgcn_mfma_f32_16x16x32_f16(al, wh, acc[t], 0, 0, 0);
        }
    }
    const int rb = blockIdx.x * 128 + wid * 16 + quad * 4;
#pragma unroll
    for (int t = 0; t < 13; ++t) {
        int c = t * 16 + l16;
        if (c < 200) {
#pragma unroll
            for (int e = 0; e < 4; ++e) {
                int r = rb + e;
                if (r < M) T[(size_t)r * 200 + c] = (_Float16)acc[t][e];
            }
        }
    }
}

// ================= propagation (200-wide) via CSR gather, 4-way unrolled edges =================
__global__ __launch_bounds__(256) void k_gather200h(const _Float16* __restrict__ t,
                                                    const float* __restrict__ dinv,
                                                    const int* __restrict__ rowptr,
                                                    const int2* __restrict__ adj,
                                                    _Float16* __restrict__ p, int n) {
    int gid = blockIdx.x * blockDim.x + threadIdx.x;
    if (gid >= n * 25) return;
    int v = gid / 25, c8 = gid - v * 25;
    const v8h* tp = (const v8h*)t;
    float w0 = dinv[v]; w0 *= w0;
    v8h tv = tp[v * 25 + c8];
    float a0[8], a1[8], a2[8], a3[8];
#pragma unroll
    for (int i = 0; i < 8; ++i) { a0[i] = (float)tv[i] * w0; a1[i] = 0.0f; a2[i] = 0.0f; a3[i] = 0.0f; }
    int lo = v ? rowptr[v - 1] : 0;
    int hi = rowptr[v];
    int j = lo;
    for (; j + 3 < hi; j += 4) {
        int2 e0 = adj[j], e1 = adj[j + 1], e2 = adj[j + 2], e3 = adj[j + 3];
        float wa = __int_as_float(e0.y), wb = __int_as_float(e1.y);
        float wc = __int_as_float(e2.y), wd = __int_as_float(e3.y);
        v8h s0 = tp[e0.x * 25 + c8];
        v8h s1 = tp[e1.x * 25 + c8];
        v8h s2 = tp[e2.x * 25 + c8];
        v8h s3 = tp[e3.x * 25 + c8];
#pragma unroll
        for (int i = 0; i < 8; ++i) {
            a0[i] += (float)s0[i] * wa;
            a1[i] += (float)s1[i] * wb;
            a2[i] += (float)s2[i] * wc;
            a3[i] += (float)s3[i] * wd;
        }
    }
    for (; j < hi; ++j) {
        int2 cw = adj[j];
        float w = __int_as_float(cw.y);
        v8h sv = tp[cw.x * 25 + c8];
#pragma unroll
        for (int i = 0; i < 8; ++i) a0[i] += (float)sv[i] * w;
    }
    v8h o;
#pragma unroll
    for (int i = 0; i < 8; ++i) o[i] = (_Float16)((a0[i] + a1[i]) + (a2[i] + a3[i]));
    ((v8h*)p)[v * 25 + c8] = o;
}

// ================= FUSED final gather + segmented pooling: 32-node windows,
// gather-grade parallelism (1563 blocks), v8h loads, f32 accum straight into pooled.
// Per graph-segment in window: lanes (c8,li) accumulate -> LDS reduce -> 200 atomics. =================
__global__ __launch_bounds__(256) void k_gpool(const _Float16* __restrict__ T,
                                               const float* __restrict__ dinv,
                                               const int* __restrict__ rowptr,
                                               const int2* __restrict__ adj,
                                               const float* __restrict__ b3,
                                               const int* __restrict__ batch, int n,
                                               float* __restrict__ pooled) {
    __shared__ float part[10][25][9];   // padded inner dim: avoids bank conflicts
    const int t = threadIdx.x;
    const int c8 = t % 25, li = t / 25;   // 250 active lanes
    const int base = blockIdx.x * 32;
    const int end = min(base + 32, n);
    const v8h* tp = (const v8h*)T;
    float4 ba = *(const float4*)(b3 + c8 * 8);
    float4 bb = *(const float4*)(b3 + c8 * 8 + 4);
    float bv[8] = {ba.x, ba.y, ba.z, ba.w, bb.x, bb.y, bb.z, bb.w};

    int seg = base;
    while (seg < end) {
        int g = batch[seg];
        // segment end: first idx in (seg, end) with batch != g (batch sorted)
        int lo2 = seg + 1, hi2 = end;
        while (lo2 < hi2) { int m = (lo2 + hi2) >> 1; if (batch[m] == g) lo2 = m + 1; else hi2 = m; }
        int segend = lo2;

        if (li < 10) {
            float acc[8];
#pragma unroll
            for (int i = 0; i < 8; ++i) acc[i] = 0.0f;
            for (int i = seg + li; i < segend; i += 10) {
                float w0 = dinv[i]; w0 *= w0;
                v8h tv = tp[(size_t)i * 25 + c8];
                float a0[8], a1[8];
#pragma unroll
                for (int q = 0; q < 8; ++q) { a0[q] = (float)tv[q] * w0; a1[q] = 0.0f; }
                int elo = i ? rowptr[i - 1] : 0;
                int ehi = rowptr[i];
                int j = elo;
                for (; j + 1 < ehi; j += 2) {
                    int2 e0 = adj[j], e1 = adj[j + 1];
                    float wa = __int_as_float(e0.y), wb = __int_as_float(e1.y);
                    v8h s0 = tp[(size_t)e0.x * 25 + c8];
                    v8h s1 = tp[(size_t)e1.x * 25 + c8];
#pragma unroll
                    for (int q = 0; q < 8; ++q) {
                        a0[q] += (float)s0[q] * wa;
                        a1[q] += (float)s1[q] * wb;
                    }
                }
                if (j < ehi) {
                    int2 cw = adj[j];
                    float w = __int_as_float(cw.y);
                    v8h sv = tp[(size_t)cw.x * 25 + c8];
#pragma unroll
                    for (int q = 0; q < 8; ++q) a0[q] += (float)sv[q] * w;
                }
#pragma unroll
                for (int q = 0; q < 8; ++q) {
                    float v = a0[q] + a1[q] + bv[q];
                    acc[q] += LEAKY(v);
                }
            }
#pragma unroll
            for (int q = 0; q < 8; ++q) part[li][c8][q] = acc[q];
        }
        __syncthreads();
        if (t < 200) {
            float s = 0.0f;
#pragma unroll
            for (int l2 = 0; l2 < 10; ++l2) s += part[l2][t >> 3][t & 7];
            atomicAdd(&pooled[g * 200 + t], s);   // col == t
        }
        __syncthreads();
        seg = segend;
    }
}

// ================= head: mean + concat + MLP per graph =================
__global__ __launch_bounds__(128) void k_headfin(const float* __restrict__ pooled,
                                                 const int* __restrict__ batch, int n_nodes,
                                                 const float* __restrict__ xs,
                                                 const float* __restrict__ Wl1,
                                                 const float* __restrict__ bl1,
                                                 const float* __restrict__ Wl2,
                                                 const float* __restrict__ bl2,
                                                 float* __restrict__ out) {
    __shared__ float grow[204];
    __shared__ float partial[2];
    __shared__ int sb[2];
    int g = blockIdx.x;
    int t = threadIdx.x;
    if (t == 0 || t == 64) {
        int target = g + (t ? 1 : 0);
        int lo = 0, hi = n_nodes;
        while (lo < hi) { int m = (lo + hi) >> 1; if (batch[m] < target) lo = m + 1; else hi = m; }
        sb[t ? 1 : 0] = lo;
    }
    __syncthreads();
    float inv = 1.0f / fmaxf((float)(sb[1] - sb[0]), 1.0f);
    for (int idx = t; idx < 200; idx += 128) grow[idx] = pooled[g * 200 + idx] * inv;
    if (t < 4) grow[200 + t] = xs[g * 4 + t];
    __syncthreads();
    float s = bl1[t];
    for (int k = 0; k < 204; ++k) s += grow[k] * Wl1[k * 128 + t];
    s = LEAKY(s);
    float hv = s * Wl2[t];
    for (int off = 32; off > 0; off >>= 1) hv += __shfl_down(hv, off, 64);
    if ((t & 63) == 0) partial[t >> 6] = hv;
    __syncthreads();
    if (t == 0) out[g] = partial[0] + partial[1] + bl2[0];
}

extern "C" void kernel_launch(void* const* d_in, const int* in_sizes, int n_in,
                              void* d_out, int out_size, void* d_ws, size_t ws_size,
                              hipStream_t stream) {
    const float* x    = (const float*)d_in[0];
    const int*   ei   = (const int*)d_in[1];
    const float* xs   = (const float*)d_in[2];
    const int*   batch= (const int*)d_in[3];
    const float* W0   = (const float*)d_in[4];
    const float* b0   = (const float*)d_in[5];
    const float* W1   = (const float*)d_in[6];
    const float* b1   = (const float*)d_in[7];
    const float* W2   = (const float*)d_in[8];
    const float* b2   = (const float*)d_in[9];
    const float* W3   = (const float*)d_in[10];
    const float* b3   = (const float*)d_in[11];
    const float* Wl1  = (const float*)d_in[12];
    const float* bl1  = (const float*)d_in[13];
    const float* Wl2  = (const float*)d_in[14];
    const float* bl2  = (const float*)d_in[15];
    float* out = (float*)d_out;

    const int N = in_sizes[0] / 4;   // 50000 nodes
    const int E = in_sizes[1] / 2;   // 400000 edges
    const int G = in_sizes[2] / 4;   // 500 graphs

    char* ws = (char*)d_ws;
    size_t off = 0;
    auto alloc = [&](size_t bytes) { void* p = ws + off; off += (bytes + 255) & ~size_t(255); return p; };
    _Float16* bufA = (_Float16*)alloc((size_t)N * 200 * sizeof(_Float16)); // GEMM outputs
    _Float16* bufB = (_Float16*)alloc((size_t)N * 200 * sizeof(_Float16)); // gather outputs
    float* dinv   = (float*)alloc((size_t)N * sizeof(float));
    float* pooled = (float*)alloc((size_t)G * 200 * sizeof(float));
    int*   cnt    = (int*)alloc((size_t)N * sizeof(int));
    int*   rowptr = (int*)alloc(((size_t)N + 1) * sizeof(int));
    int*   bsum   = (int*)alloc(256 * sizeof(int));
    int2*  adj    = (int2*)alloc((size_t)E * sizeof(int2));
    _Float16* Wth[3]; _Float16* Wtl[3];
    for (int i = 0; i < 3; ++i) {
        Wth[i] = (_Float16*)alloc(208 * 224 * sizeof(_Float16));
        Wtl[i] = (_Float16*)alloc(208 * 224 * sizeof(_Float16));
    }

    const int B = 256;
    const int nblk = (N + 255) / 256;

    // W splits (3 layers, one launch) + cnt zeroing (fused; must precede k_count)
    dim3 sg((224 * 208 + B - 1) / B, 3);
    k_splitW3<<<sg, B, 0, stream>>>(W1, W2, W3, Wth[0], Wtl[0], Wth[1], Wtl[1], Wth[2], Wtl[2],
                                    cnt, N);

    // CSR build (by destination) + norms + pooled zero; fill uses shifted rowptr convention
    k_count<<<(E + B - 1) / B, B, 0, stream>>>(ei, cnt, E);
    k_scan1<<<nblk, 256, 0, stream>>>(cnt, rowptr, bsum, N);
    k_scan3<<<nblk, 256, 0, stream>>>(rowptr, bsum, cnt, dinv, N, pooled, G * 200);
    k_fill<<<(E + B - 1) / B, B, 0, stream>>>(ei, dinv, rowptr, adj, E);

    const int gblocks = (N * 25 + 255) / 256;
    const int mblocks = (N + 127) / 128;

    // layer 1: GEMM with fused 4-wide gather (A = Ahat x @ W0 + b0 synthesized in-kernel)
    k_gemm200_mfma_l0<<<mblocks, 512, 0, stream>>>(x, dinv, rowptr, adj, W0, b0,
                                                   Wth[0], Wtl[0], bufA, N);
    k_gather200h<<<gblocks, 256, 0, stream>>>(bufA, dinv, rowptr, adj, bufB, N);

    // layers 2-3
    k_gemm200_mfma<<<mblocks, 512, 0, stream>>>(bufB, b1, Wth[1], Wtl[1], bufA, N);
    k_gather200h<<<gblocks, 256, 0, stream>>>(bufA, dinv, rowptr, adj, bufB, N);
    k_gemm200_mfma<<<mblocks, 512, 0, stream>>>(bufB, b2, Wth[2], Wtl[2], bufA, N);

    // final: fused gather + segmented pooling (f32 accum, no 20MB round-trip), then head MLP
    k_gpool<<<(N + 31) / 32, 256, 0, stream>>>(bufA, dinv, rowptr, adj, b3, batch, N, pooled);
    k_headfin<<<G, 128, 0, stream>>>(pooled, batch, N, xs, Wl1, bl1, Wl2, bl2, out);
}